// Round 8
// baseline (264.938 us; speedup 1.0000x reference)
//
#include <hip/hip_runtime.h>

typedef unsigned short ushort_t;
typedef __bf16 bf16x8 __attribute__((ext_vector_type(8)));
typedef ushort_t u16x8 __attribute__((ext_vector_type(8)));
typedef float f32x4 __attribute__((ext_vector_type(4)));
typedef unsigned int u32x2 __attribute__((ext_vector_type(2)));
typedef short s16x4 __attribute__((ext_vector_type(4)));

#define DEVI __device__ __forceinline__

// Problem dims
constexpr int Ed = 1024;   // embed
constexpr int Hh = 16;     // heads
constexpr int Dd = 64;     // head dim
constexpr int Ss = 2048;   // seq
constexpr int Mm = 4096;   // B*S rows

constexpr int NX4 = Mm * Ed / 4;
constexpr int NW4 = Ed * Ed / 4;

DEVI ushort_t f2bf(float f) {      // RNE (cold paths only)
    union { float f; unsigned int i; } v; v.f = f;
    unsigned int r = v.i + 0x7fffu + ((v.i >> 16) & 1u);
    return (ushort_t)(r >> 16);
}
DEVI ushort_t f2bf_hi(float f) {   // truncation: compiles to *_d16_hi store, 0 VALU
    union { float f; unsigned int i; } v; v.f = f;
    return (ushort_t)(v.i >> 16);
}
DEVI unsigned int fbits(float f) {
    union { float f; unsigned int i; } v; v.f = f;
    return v.i;
}
DEVI float fast_exp2(float x) {    // raw v_exp_f32 (no ocml wrapper)
    float r;
    asm("v_exp_f32 %0, %1" : "=v"(r) : "v"(x));
    return r;
}
DEVI unsigned int pkbf(float lo, float hi) {   // trunc pack 2 f32 -> 2 bf16
    return (fbits(hi) & 0xffff0000u) | (fbits(lo) >> 16);
}

// K=16 bf16 MFMA (PV step). Builtin chain + asm fallback (ISA: v_mfma_f32_16x16x16_bf16).
DEVI f32x4 mfma16(s16x4 a, s16x4 b, f32x4 c) {
#if __has_builtin(__builtin_amdgcn_mfma_f32_16x16x16bf16_1k)
    return __builtin_amdgcn_mfma_f32_16x16x16bf16_1k(a, b, c, 0, 0, 0);
#elif __has_builtin(__builtin_amdgcn_mfma_f32_16x16x16_bf16_1k)
    return __builtin_amdgcn_mfma_f32_16x16x16_bf16_1k(a, b, c, 0, 0, 0);
#else
    f32x4 d = c;
    asm volatile("v_mfma_f32_16x16x16_bf16 %0, %1, %2, %0"
                 : "+v"(d) : "v"(a), "v"(b));
    return d;
#endif
}

// One-shot fp32 -> bf16 conversion of x + 4 weight matrices (RNE).
__global__ __launch_bounds__(256) void cvt_all(
    const float* __restrict__ x,  const float* __restrict__ Wq,
    const float* __restrict__ Wk, const float* __restrict__ Wv,
    const float* __restrict__ Wo,
    ushort_t* __restrict__ xb,  ushort_t* __restrict__ Wqb,
    ushort_t* __restrict__ Wkb, ushort_t* __restrict__ Wvb,
    ushort_t* __restrict__ Wob)
{
    int i = blockIdx.x * 256 + threadIdx.x;
    const float* s; ushort_t* d; int off;
    if (i < NX4)                { s = x;  d = xb;  off = i; }
    else if (i < NX4 + NW4)     { s = Wq; d = Wqb; off = i - NX4; }
    else if (i < NX4 + 2 * NW4) { s = Wk; d = Wkb; off = i - NX4 - NW4; }
    else if (i < NX4 + 3 * NW4) { s = Wv; d = Wvb; off = i - NX4 - 2 * NW4; }
    else                        { s = Wo; d = Wob; off = i - NX4 - 3 * NW4; }
    float4 v = ((const float4*)s)[off];
    ushort4 o; o.x = f2bf(v.x); o.y = f2bf(v.y); o.z = f2bf(v.z); o.w = f2bf(v.w);
    ((ushort4*)d)[off] = o;
}

// async global->LDS, 16B per lane
DEVI void gld16(const void* g, void* l) {
    __builtin_amdgcn_global_load_lds(
        (__attribute__((address_space(1))) void*)(g),
        (__attribute__((address_space(3))) void*)(l), 16, 0, 0);
}

// ---------------- NT GEMM core (m97 pattern + XOR-swizzled LDS) ------------
DEVI void gemm_core(const ushort_t* __restrict__ A, const ushort_t* __restrict__ W,
                    ushort_t* As, ushort_t* Bs, int tm, int tn, int K,
                    f32x4 acc[4][4])
{
    const int tid  = threadIdx.x;
    const int w    = tid >> 6;
    const int lane = tid & 63;
    const int quad = lane >> 4;
    const int l15  = lane & 15;
    const int wy   = w >> 1, wx = w & 1;
    const int rowc = lane >> 3;                      // row within 8-row chunk
    const int col8s = (((lane & 7) ^ rowc) * 8);     // swizzled source granule
    const int swq  = l15 & 7;                        // read-swizzle row term

    for (int k0 = 0; k0 < K; k0 += 64) {
        __syncthreads();
#pragma unroll
        for (int i = 0; i < 4; ++i) {
            int chunk = w * 4 + i;
            int row = chunk * 8 + rowc;              // row&7 == rowc
            gld16(A + (size_t)(tm + row) * K + k0 + col8s, (char*)As + chunk * 1024);
            gld16(W + (size_t)(tn + row) * K + k0 + col8s, (char*)Bs + chunk * 1024);
        }
        __syncthreads();
#pragma unroll
        for (int ks = 0; ks < 64; ks += 32) {
            const int k4 = ks >> 3;                  // 0 or 4
            bf16x8 a[4], b[4];
#pragma unroll
            for (int mi = 0; mi < 4; ++mi)
                a[mi] = *(const bf16x8*)&As[(wy * 64 + mi * 16 + l15) * 64
                                            + (((quad + k4) ^ swq) * 8)];
#pragma unroll
            for (int ni = 0; ni < 4; ++ni)
                b[ni] = *(const bf16x8*)&Bs[(wx * 64 + ni * 16 + l15) * 64
                                            + (((quad + k4) ^ swq) * 8)];
#pragma unroll
            for (int mi = 0; mi < 4; ++mi)
#pragma unroll
                for (int ni = 0; ni < 4; ++ni)
                    acc[mi][ni] = __builtin_amdgcn_mfma_f32_16x16x32_bf16(
                        a[mi], b[ni], acc[mi][ni], 0, 0, 0);
        }
    }
}

// Fused QKV projection. Q,K stored [B,H,S,D]; V stored [B,H,D,S].
__global__ __launch_bounds__(256, 3) void qkv_gemm(
    const ushort_t* __restrict__ x,
    const ushort_t* __restrict__ Wq, const float* __restrict__ bq,
    const ushort_t* __restrict__ Wk, const float* __restrict__ bk,
    const ushort_t* __restrict__ Wv, const float* __restrict__ bv,
    ushort_t* __restrict__ qo, ushort_t* __restrict__ ko, ushort_t* __restrict__ vto)
{
    __shared__ __align__(16) ushort_t As[128 * 64];
    __shared__ __align__(16) ushort_t Bs[128 * 64];
    const ushort_t* W; const float* bias; ushort_t* outp; int vmode;
    if (blockIdx.z == 0)      { W = Wq; bias = bq; outp = qo;  vmode = 0; }
    else if (blockIdx.z == 1) { W = Wk; bias = bk; outp = ko;  vmode = 0; }
    else                      { W = Wv; bias = bv; outp = vto; vmode = 1; }

    const int tm = blockIdx.x * 128, tn = blockIdx.y * 128;
    f32x4 acc[4][4] = {};
    gemm_core(x, W, As, Bs, tm, tn, Ed, acc);

    const int tid = threadIdx.x, w = tid >> 6, lane = tid & 63;
    const int quad = lane >> 4, l15 = lane & 15;
    const int wy = w >> 1, wx = w & 1;
    if (vmode == 0) {
#pragma unroll
        for (int ni = 0; ni < 4; ++ni) {
            int gc = tn + wx * 64 + ni * 16 + l15;
            float bb = bias[gc];
            int h = gc >> 6, d = gc & 63;
#pragma unroll
            for (int mi = 0; mi < 4; ++mi) {
#pragma unroll
                for (int r = 0; r < 4; ++r) {
                    int gr = tm + wy * 64 + mi * 16 + quad * 4 + r;
                    int b_ = gr >> 11, s_ = gr & 2047;
                    float v = acc[mi][ni][r] + bb;
                    outp[((size_t)(b_ * Hh + h) * Ss + s_) * Dd + d] = f2bf_hi(v);
                }
            }
        }
    } else {
#pragma unroll
        for (int ni = 0; ni < 4; ++ni) {
            int gc = tn + wx * 64 + ni * 16 + l15;
            float bb = bias[gc];
            int h = gc >> 6, d = gc & 63;
#pragma unroll
            for (int mi = 0; mi < 4; ++mi) {
                int gr0 = tm + wy * 64 + mi * 16 + quad * 4;   // r=0; same batch for r=0..3
                int b_ = gr0 >> 11, s0 = gr0 & 2047;
                u32x2 pk;
                pk[0] = pkbf(acc[mi][ni][0] + bb, acc[mi][ni][1] + bb);
                pk[1] = pkbf(acc[mi][ni][2] + bb, acc[mi][ni][3] + bb);
                *(u32x2*)&outp[((size_t)(b_ * Hh + h) * Dd + d) * Ss + s0] = pk;
            }
        }
    }
}

// Output projection: out = ctx @ Wo^T + bo, [M,E] FP32. Penalty fused in block (0,0).
__global__ __launch_bounds__(256, 3) void out_gemm(
    const ushort_t* __restrict__ ctx, const ushort_t* __restrict__ Wo,
    const float* __restrict__ bo, const float* __restrict__ z,
    float* __restrict__ out)
{
    __shared__ __align__(16) ushort_t As[128 * 64];
    __shared__ __align__(16) ushort_t Bs[64 * 64];
    const int tm = blockIdx.x * 128, tn = blockIdx.y * 64;

    const int tid  = threadIdx.x;
    const int w    = tid >> 6;
    const int lane = tid & 63;
    const int quad = lane >> 4;
    const int l15  = lane & 15;
    const int wy   = w >> 1, wx = w & 1;
    const int rowc = lane >> 3;
    const int col8s = (((lane & 7) ^ rowc) * 8);
    const int swq  = l15 & 7;

    f32x4 acc[4][2] = {};
    for (int k0 = 0; k0 < Ed; k0 += 64) {
        __syncthreads();
#pragma unroll
        for (int i = 0; i < 4; ++i) {
            int chunk = w * 4 + i;
            int row = chunk * 8 + rowc;
            gld16(ctx + (size_t)(tm + row) * Ed + k0 + col8s, (char*)As + chunk * 1024);
        }
#pragma unroll
        for (int i = 0; i < 2; ++i) {
            int chunk = w * 2 + i;
            int row = chunk * 8 + rowc;
            gld16(Wo + (size_t)(tn + row) * Ed + k0 + col8s, (char*)Bs + chunk * 1024);
        }
        __syncthreads();
#pragma unroll
        for (int ks = 0; ks < 64; ks += 32) {
            const int k4 = ks >> 3;
            bf16x8 a[4], b[2];
#pragma unroll
            for (int mi = 0; mi < 4; ++mi)
                a[mi] = *(const bf16x8*)&As[(wy * 64 + mi * 16 + l15) * 64
                                            + (((quad + k4) ^ swq) * 8)];
#pragma unroll
            for (int ni = 0; ni < 2; ++ni)
                b[ni] = *(const bf16x8*)&Bs[(wx * 32 + ni * 16 + l15) * 64
                                            + (((quad + k4) ^ swq) * 8)];
#pragma unroll
            for (int mi = 0; mi < 4; ++mi)
#pragma unroll
                for (int ni = 0; ni < 2; ++ni)
                    acc[mi][ni] = __builtin_amdgcn_mfma_f32_16x16x32_bf16(
                        a[mi], b[ni], acc[mi][ni], 0, 0, 0);
        }
    }

#pragma unroll
    for (int ni = 0; ni < 2; ++ni) {
        int gc = tn + wx * 32 + ni * 16 + l15;
        float bb = bo[gc];
#pragma unroll
        for (int mi = 0; mi < 4; ++mi)
#pragma unroll
            for (int r = 0; r < 4; ++r) {
                int gr = tm + wy * 64 + mi * 16 + quad * 4 + r;
                out[(size_t)gr * Ed + gc] = acc[mi][ni][r] + bb;
            }
    }

    if (blockIdx.x == 0 && blockIdx.y == 0 && tid == 0) {
        float s = 0.f;
        for (int hh = 0; hh < Hh; ++hh) s += 1.f / (1.f + __expf(-z[hh]));
        out[(size_t)Mm * Ed] = s * 0.01f;
    }
}

// Flash attention v24: SWAPPED QK^T + K=16 PV => P never leaves registers.
// mfma(K,Q) gives lane(quad,l15) P[key=ni*16+quad*4+r][q=own l15]; the K=16
// PV mfma's B-operand wants P^T[k=quad*4..+4][q=l15] -- exactly those 4 regs.
// A-operand = V^T[d=l15][k=quad*4..+4]: 8B contiguous load from [B,H,D,S].
// Eliminates per-kt 128 ds_write_b16 + 16 ds_read_b128 + 2 lgkm drains +
// 35KB LDS (v21-23's Ps path -- hiding it was neutral (v23); only removal
// is left). lsum becomes per-lane scalar (2 end shuffles); ctx epilogue
// becomes 8B packed stores. K LDS dbuf + 1 barrier/kt unchanged (v22 proved
// LDS-K is needed). grid = (S/128, B*H) = 512 blocks, 2/CU. LDS 32.8KB.
__global__ __launch_bounds__(256, 2) void attn(
    const ushort_t* __restrict__ Q, const ushort_t* __restrict__ Kk,
    const ushort_t* __restrict__ Vt, const float* __restrict__ z,
    ushort_t* __restrict__ ctx)
{
    __shared__ __align__(16) ushort_t Ks[2][128 * 64];   // swizzled [key][d], dbuf 32KB

    const int tid = threadIdx.x, w = tid >> 6, lane = tid & 63;
    const int quad = lane >> 4, l15 = lane & 15;
    const int lin = blockIdx.x + 16 * blockIdx.y;   // 0..511 (gridDim.x = 16)
    const int qt = lin >> 5;                        // 0..15 (128-row q tile)
    const int bh = (lin & 7) * 4 + ((lin >> 3) & 3);// 0..31, XCD-local heads
    const int h = bh & (Hh - 1), b_ = bh >> 4;
    const size_t base = (size_t)bh * Ss * Dd;

    const float gate = 1.f / (1.f + __expf(-z[h]));
    const float scl2 = gate * 0.125f * 1.44269504f;  // gate/sqrt(D) * log2(e)

    bf16x8 aQ[2][2];   // B-operand of swapped QK^T: Q[q=own l15][d]
#pragma unroll
    for (int m = 0; m < 2; ++m)
#pragma unroll
        for (int c = 0; c < 2; ++c)
            aQ[m][c] = *(const bf16x8*)&Q[base
                + (size_t)(qt * 128 + w * 32 + m * 16 + l15) * Dd + c * 32 + quad * 8];

    // K staging: wave w owns rows w*32 .. w*32+31 (4 chunks of 8 rows)
    const int rowc = lane >> 3;                     // 0..7
    const int gs   = ((lane & 7) ^ rowc) * 8;       // swizzled source granule
    const ushort_t* kSrc[4];
#pragma unroll
    for (int i = 0; i < 4; ++i)
        kSrc[i] = Kk + base + (size_t)(w * 32 + i * 8 + rowc) * Dd + gs;
    // direct-V for K=16 PV: A-operand row d = ni*16+l15, keys quad*4..+4 (8B)
    const ushort_t* vBase = Vt + base + (size_t)l15 * Ss + quad * 4;

    f32x4 accO[2][4] = {};        // accO[m][ni][r] = O[q=m*16+l15][d=ni*16+quad*4+r]
    float lsum[2] = {0.f, 0.f};   // per-lane partial for q = m*16+l15 (own keys only)

    const int swq = (l15 & 7) * 8;

    // prologue: stage K-tile 0 (128 keys) into Ks[0]
#pragma unroll
    for (int i = 0; i < 4; ++i)
        gld16(kSrc[i], (char*)Ks[0] + (w * 4 + i) * 1024);

    for (int kt = 0; kt < Ss / 128; ++kt) {
        const int cur = kt & 1, nxt = cur ^ 1;
        __syncthreads();   // K(kt) visible; all waves done with Ks[nxt] of kt-1

        if (kt + 1 < Ss / 128) {   // prefetch K(kt+1) into Ks[nxt]
#pragma unroll
            for (int i = 0; i < 4; ++i)
                gld16(kSrc[i] + (size_t)(kt + 1) * 128 * Dd,
                      (char*)Ks[nxt] + (w * 4 + i) * 1024);
        }

#pragma unroll
        for (int sub = 0; sub < 2; ++sub) {
            const int key0 = kt * 128 + sub * 64;

            // V^T fragments (A-operand, K=16): vf16[kc][ni], 8B each, L2-local
            s16x4 vf16[4][4];
#pragma unroll
            for (int kc = 0; kc < 4; ++kc)
#pragma unroll
                for (int ni = 0; ni < 4; ++ni)
                    vf16[kc][ni] = *(const s16x4*)(vBase + (size_t)(ni * 16) * Ss
                                                   + key0 + kc * 16);

            // S^T = K Q (swapped): sT[m][ni][r] = S[key=ni*16+quad*4+r][q=m*16+l15]
            f32x4 sT[2][4] = {};
            __builtin_amdgcn_s_setprio(1);
#pragma unroll
            for (int ni = 0; ni < 4; ++ni) {
                bf16x8 k0f = *(const bf16x8*)&Ks[cur][(sub * 64 + ni * 16 + l15) * 64 + ((quad * 8) ^ swq)];
                bf16x8 k1f = *(const bf16x8*)&Ks[cur][(sub * 64 + ni * 16 + l15) * 64 + (((quad + 4) * 8) ^ swq)];
#pragma unroll
                for (int m = 0; m < 2; ++m) {
                    sT[m][ni] = __builtin_amdgcn_mfma_f32_16x16x32_bf16(k0f, aQ[m][0], sT[m][ni], 0, 0, 0);
                    sT[m][ni] = __builtin_amdgcn_mfma_f32_16x16x32_bf16(k1f, aQ[m][1], sT[m][ni], 0, 0, 0);
                }
            }
            __builtin_amdgcn_s_setprio(0);

            // softmax in-register: p = exp2(s*scl2); pack to bf16 pairs (PV B-operand)
            s16x4 pb[2][4];
#pragma unroll
            for (int m = 0; m < 2; ++m)
#pragma unroll
                for (int ni = 0; ni < 4; ++ni) {
                    float p0 = fast_exp2(sT[m][ni][0] * scl2);
                    float p1 = fast_exp2(sT[m][ni][1] * scl2);
                    float p2 = fast_exp2(sT[m][ni][2] * scl2);
                    float p3 = fast_exp2(sT[m][ni][3] * scl2);
                    lsum[m] += (p0 + p1) + (p2 + p3);
                    union { unsigned int u[2]; s16x4 v; } uu;
                    uu.u[0] = pkbf(p0, p1);
                    uu.u[1] = pkbf(p2, p3);
                    pb[m][ni] = uu.v;
                }

            // O^T += V^T P^T  (K=16 MFMA; everything in registers)
            __builtin_amdgcn_s_setprio(1);
#pragma unroll
            for (int kc = 0; kc < 4; ++kc)
#pragma unroll
                for (int m = 0; m < 2; ++m)
#pragma unroll
                    for (int ni = 0; ni < 4; ++ni)
                        accO[m][ni] = mfma16(vf16[kc][ni], pb[m][kc], accO[m][ni]);
            __builtin_amdgcn_s_setprio(0);
        }
    }

    // lsum: sum partials across the 4 quads holding the same q (lanes l15+16k)
#pragma unroll
    for (int m = 0; m < 2; ++m) {
        lsum[m] += __shfl_xor(lsum[m], 16);
        lsum[m] += __shfl_xor(lsum[m], 32);
    }

    // epilogue: lane owns q = m*16+l15; d = ni*16+quad*4+r consecutive -> 8B stores
#pragma unroll
    for (int m = 0; m < 2; ++m) {
        int srow = qt * 128 + w * 32 + m * 16 + l15;
        float inv = 1.f / lsum[m];
        ushort_t* crow = ctx + ((size_t)(b_ * Ss + srow)) * Ed + h * Dd + quad * 4;
#pragma unroll
        for (int ni = 0; ni < 4; ++ni) {
            u32x2 pk;
            pk[0] = pkbf(accO[m][ni][0] * inv, accO[m][ni][1] * inv);
            pk[1] = pkbf(accO[m][ni][2] * inv, accO[m][ni][3] * inv);
            *(u32x2*)&crow[ni * 16] = pk;
        }
    }
}

extern "C" void kernel_launch(void* const* d_in, const int* in_sizes, int n_in,
                              void* d_out, int out_size, void* d_ws, size_t ws_size,
                              hipStream_t stream) {
    const float* x  = (const float*)d_in[0];
    const float* Wq = (const float*)d_in[1];
    const float* bq = (const float*)d_in[2];
    const float* Wk = (const float*)d_in[3];
    const float* bk = (const float*)d_in[4];
    const float* Wv = (const float*)d_in[5];
    const float* bv = (const float*)d_in[6];
    const float* Wo = (const float*)d_in[7];
    const float* bo = (const float*)d_in[8];
    const float* z  = (const float*)d_in[9];
    float* out = (float*)d_out;

    ushort_t* xb  = (ushort_t*)d_ws;              // [M,E]     8 MB
    ushort_t* Wqb = xb  + (size_t)Mm * Ed;        // [E,E]     2 MB
    ushort_t* Wkb = Wqb + (size_t)Ed * Ed;
    ushort_t* Wvb = Wkb + (size_t)Ed * Ed;
    ushort_t* Wob = Wvb + (size_t)Ed * Ed;
    ushort_t* qw  = Wob + (size_t)Ed * Ed;        // [B,H,S,D] 8 MB
    ushort_t* kw  = qw + (size_t)Mm * Ed;         // [B,H,S,D] 8 MB
    ushort_t* vT  = kw + (size_t)Mm * Ed;         // [B,H,D,S] 8 MB
    ushort_t* cx  = vT + (size_t)Mm * Ed;         // [B,S,E]   8 MB

    dim3 blk(256);
    cvt_all<<<dim3((NX4 + 4 * NW4) / 256), blk, 0, stream>>>(
        x, Wq, Wk, Wv, Wo, xb, Wqb, Wkb, Wvb, Wob);
    qkv_gemm<<<dim3(Mm / 128, Ed / 128, 3), blk, 0, stream>>>(
        xb, Wqb, bq, Wkb, bk, Wvb, bv, qw, kw, vT);
    attn<<<dim3(Ss / 128, 2 * Hh), blk, 0, stream>>>(qw, kw, vT, z, cx);
    out_gemm<<<dim3(Mm / 128, Ed / 64), blk, 0, stream>>>(cx, Wob, bo, z, out);
}

// Round 9
// 211.676 us; speedup vs baseline: 1.2516x; 1.2516x over previous
//
#include <hip/hip_runtime.h>

typedef unsigned short ushort_t;
typedef __bf16 bf16x8 __attribute__((ext_vector_type(8)));
typedef ushort_t u16x8 __attribute__((ext_vector_type(8)));
typedef float f32x4 __attribute__((ext_vector_type(4)));
typedef unsigned int u32x2 __attribute__((ext_vector_type(2)));

#define DEVI __device__ __forceinline__

// Problem dims
constexpr int Ed = 1024;   // embed
constexpr int Hh = 16;     // heads
constexpr int Dd = 64;     // head dim
constexpr int Ss = 2048;   // seq
constexpr int Mm = 4096;   // B*S rows

constexpr int NX4 = Mm * Ed / 4;
constexpr int NW4 = Ed * Ed / 4;

DEVI ushort_t f2bf(float f) {      // RNE (cold paths only)
    union { float f; unsigned int i; } v; v.f = f;
    unsigned int r = v.i + 0x7fffu + ((v.i >> 16) & 1u);
    return (ushort_t)(r >> 16);
}
DEVI ushort_t f2bf_hi(float f) {   // truncation: compiles to *_d16_hi store, 0 VALU
    union { float f; unsigned int i; } v; v.f = f;
    return (ushort_t)(v.i >> 16);
}
DEVI unsigned int fbits(float f) {
    union { float f; unsigned int i; } v; v.f = f;
    return v.i;
}
DEVI float fast_exp2(float x) {    // raw v_exp_f32 (no ocml wrapper)
    float r;
    asm("v_exp_f32 %0, %1" : "=v"(r) : "v"(x));
    return r;
}
DEVI unsigned int pkbf(float lo, float hi) {   // trunc pack 2 f32 -> 2 bf16
    return (fbits(hi) & 0xffff0000u) | (fbits(lo) >> 16);
}

// One-shot fp32 -> bf16 conversion of x + 4 weight matrices (RNE).
__global__ __launch_bounds__(256) void cvt_all(
    const float* __restrict__ x,  const float* __restrict__ Wq,
    const float* __restrict__ Wk, const float* __restrict__ Wv,
    const float* __restrict__ Wo,
    ushort_t* __restrict__ xb,  ushort_t* __restrict__ Wqb,
    ushort_t* __restrict__ Wkb, ushort_t* __restrict__ Wvb,
    ushort_t* __restrict__ Wob)
{
    int i = blockIdx.x * 256 + threadIdx.x;
    const float* s; ushort_t* d; int off;
    if (i < NX4)                { s = x;  d = xb;  off = i; }
    else if (i < NX4 + NW4)     { s = Wq; d = Wqb; off = i - NX4; }
    else if (i < NX4 + 2 * NW4) { s = Wk; d = Wkb; off = i - NX4 - NW4; }
    else if (i < NX4 + 3 * NW4) { s = Wv; d = Wvb; off = i - NX4 - 2 * NW4; }
    else                        { s = Wo; d = Wob; off = i - NX4 - 3 * NW4; }
    float4 v = ((const float4*)s)[off];
    ushort4 o; o.x = f2bf(v.x); o.y = f2bf(v.y); o.z = f2bf(v.z); o.w = f2bf(v.w);
    ((ushort4*)d)[off] = o;
}

// async global->LDS, 16B per lane
DEVI void gld16(const void* g, void* l) {
    __builtin_amdgcn_global_load_lds(
        (__attribute__((address_space(1))) void*)(g),
        (__attribute__((address_space(3))) void*)(l), 16, 0, 0);
}

// ---------------- NT GEMM core (m97 pattern + XOR-swizzled LDS) ------------
DEVI void gemm_core(const ushort_t* __restrict__ A, const ushort_t* __restrict__ W,
                    ushort_t* As, ushort_t* Bs, int tm, int tn, int K,
                    f32x4 acc[4][4])
{
    const int tid  = threadIdx.x;
    const int w    = tid >> 6;
    const int lane = tid & 63;
    const int quad = lane >> 4;
    const int l15  = lane & 15;
    const int wy   = w >> 1, wx = w & 1;
    const int rowc = lane >> 3;                      // row within 8-row chunk
    const int col8s = (((lane & 7) ^ rowc) * 8);     // swizzled source granule
    const int swq  = l15 & 7;                        // read-swizzle row term

    for (int k0 = 0; k0 < K; k0 += 64) {
        __syncthreads();
#pragma unroll
        for (int i = 0; i < 4; ++i) {
            int chunk = w * 4 + i;
            int row = chunk * 8 + rowc;              // row&7 == rowc
            gld16(A + (size_t)(tm + row) * K + k0 + col8s, (char*)As + chunk * 1024);
            gld16(W + (size_t)(tn + row) * K + k0 + col8s, (char*)Bs + chunk * 1024);
        }
        __syncthreads();
#pragma unroll
        for (int ks = 0; ks < 64; ks += 32) {
            const int k4 = ks >> 3;                  // 0 or 4
            bf16x8 a[4], b[4];
#pragma unroll
            for (int mi = 0; mi < 4; ++mi)
                a[mi] = *(const bf16x8*)&As[(wy * 64 + mi * 16 + l15) * 64
                                            + (((quad + k4) ^ swq) * 8)];
#pragma unroll
            for (int ni = 0; ni < 4; ++ni)
                b[ni] = *(const bf16x8*)&Bs[(wx * 64 + ni * 16 + l15) * 64
                                            + (((quad + k4) ^ swq) * 8)];
#pragma unroll
            for (int mi = 0; mi < 4; ++mi)
#pragma unroll
                for (int ni = 0; ni < 4; ++ni)
                    acc[mi][ni] = __builtin_amdgcn_mfma_f32_16x16x32_bf16(
                        a[mi], b[ni], acc[mi][ni], 0, 0, 0);
        }
    }
}

// Fused QKV projection. Q,K stored [B,H,S,D]; V stored [B,H,D,S].
// Q epilogue pre-scales by scl2[h] = sigmoid(z[h])*0.125*log2e, so attn's
// softmax is p = exp2(S) directly (saves 64 v_mul/kt in attn's hot loop).
__global__ __launch_bounds__(256, 3) void qkv_gemm(
    const ushort_t* __restrict__ x,
    const ushort_t* __restrict__ Wq, const float* __restrict__ bq,
    const ushort_t* __restrict__ Wk, const float* __restrict__ bk,
    const ushort_t* __restrict__ Wv, const float* __restrict__ bv,
    const float* __restrict__ z,
    ushort_t* __restrict__ qo, ushort_t* __restrict__ ko, ushort_t* __restrict__ vto)
{
    __shared__ __align__(16) ushort_t As[128 * 64];
    __shared__ __align__(16) ushort_t Bs[128 * 64];
    const ushort_t* W; const float* bias; ushort_t* outp; int vmode;
    if (blockIdx.z == 0)      { W = Wq; bias = bq; outp = qo;  vmode = 0; }
    else if (blockIdx.z == 1) { W = Wk; bias = bk; outp = ko;  vmode = 0; }
    else                      { W = Wv; bias = bv; outp = vto; vmode = 1; }

    const int tm = blockIdx.x * 128, tn = blockIdx.y * 128;
    f32x4 acc[4][4] = {};
    gemm_core(x, W, As, Bs, tm, tn, Ed, acc);

    const int tid = threadIdx.x, w = tid >> 6, lane = tid & 63;
    const int quad = lane >> 4, l15 = lane & 15;
    const int wy = w >> 1, wx = w & 1;
    if (vmode == 0) {
#pragma unroll
        for (int ni = 0; ni < 4; ++ni) {
            int gc = tn + wx * 64 + ni * 16 + l15;
            float bb = bias[gc];
            int h = gc >> 6, d = gc & 63;
            float sc = 1.f;
            if (blockIdx.z == 0)   // Q: fold softmax scale (gate/sqrt(D)*log2e)
                sc = (1.f / (1.f + __expf(-z[h]))) * 0.18033688f;
#pragma unroll
            for (int mi = 0; mi < 4; ++mi) {
#pragma unroll
                for (int r = 0; r < 4; ++r) {
                    int gr = tm + wy * 64 + mi * 16 + quad * 4 + r;
                    int b_ = gr >> 11, s_ = gr & 2047;
                    float v = (acc[mi][ni][r] + bb) * sc;
                    outp[((size_t)(b_ * Hh + h) * Ss + s_) * Dd + d] = f2bf_hi(v);
                }
            }
        }
    } else {
#pragma unroll
        for (int ni = 0; ni < 4; ++ni) {
            int gc = tn + wx * 64 + ni * 16 + l15;
            float bb = bias[gc];
            int h = gc >> 6, d = gc & 63;
#pragma unroll
            for (int mi = 0; mi < 4; ++mi) {
                int gr0 = tm + wy * 64 + mi * 16 + quad * 4;   // r=0; same batch for r=0..3
                int b_ = gr0 >> 11, s0 = gr0 & 2047;
                u32x2 pk;
                pk[0] = pkbf(acc[mi][ni][0] + bb, acc[mi][ni][1] + bb);
                pk[1] = pkbf(acc[mi][ni][2] + bb, acc[mi][ni][3] + bb);
                *(u32x2*)&outp[((size_t)(b_ * Hh + h) * Dd + d) * Ss + s0] = pk;
            }
        }
    }
}

// Output projection: out = ctx @ Wo^T + bo, [M,E] FP32. Penalty fused in block (0,0).
__global__ __launch_bounds__(256, 3) void out_gemm(
    const ushort_t* __restrict__ ctx, const ushort_t* __restrict__ Wo,
    const float* __restrict__ bo, const float* __restrict__ z,
    float* __restrict__ out)
{
    __shared__ __align__(16) ushort_t As[128 * 64];
    __shared__ __align__(16) ushort_t Bs[64 * 64];
    const int tm = blockIdx.x * 128, tn = blockIdx.y * 64;

    const int tid  = threadIdx.x;
    const int w    = tid >> 6;
    const int lane = tid & 63;
    const int quad = lane >> 4;
    const int l15  = lane & 15;
    const int wy   = w >> 1, wx = w & 1;
    const int rowc = lane >> 3;
    const int col8s = (((lane & 7) ^ rowc) * 8);
    const int swq  = l15 & 7;

    f32x4 acc[4][2] = {};
    for (int k0 = 0; k0 < Ed; k0 += 64) {
        __syncthreads();
#pragma unroll
        for (int i = 0; i < 4; ++i) {
            int chunk = w * 4 + i;
            int row = chunk * 8 + rowc;
            gld16(ctx + (size_t)(tm + row) * Ed + k0 + col8s, (char*)As + chunk * 1024);
        }
#pragma unroll
        for (int i = 0; i < 2; ++i) {
            int chunk = w * 2 + i;
            int row = chunk * 8 + rowc;
            gld16(Wo + (size_t)(tn + row) * Ed + k0 + col8s, (char*)Bs + chunk * 1024);
        }
        __syncthreads();
#pragma unroll
        for (int ks = 0; ks < 64; ks += 32) {
            const int k4 = ks >> 3;
            bf16x8 a[4], b[2];
#pragma unroll
            for (int mi = 0; mi < 4; ++mi)
                a[mi] = *(const bf16x8*)&As[(wy * 64 + mi * 16 + l15) * 64
                                            + (((quad + k4) ^ swq) * 8)];
#pragma unroll
            for (int ni = 0; ni < 2; ++ni)
                b[ni] = *(const bf16x8*)&Bs[(wx * 32 + ni * 16 + l15) * 64
                                            + (((quad + k4) ^ swq) * 8)];
#pragma unroll
            for (int mi = 0; mi < 4; ++mi)
#pragma unroll
                for (int ni = 0; ni < 2; ++ni)
                    acc[mi][ni] = __builtin_amdgcn_mfma_f32_16x16x32_bf16(
                        a[mi], b[ni], acc[mi][ni], 0, 0, 0);
        }
    }

#pragma unroll
    for (int ni = 0; ni < 2; ++ni) {
        int gc = tn + wx * 32 + ni * 16 + l15;
        float bb = bo[gc];
#pragma unroll
        for (int mi = 0; mi < 4; ++mi)
#pragma unroll
            for (int r = 0; r < 4; ++r) {
                int gr = tm + wy * 64 + mi * 16 + quad * 4 + r;
                out[(size_t)gr * Ed + gc] = acc[mi][ni][r] + bb;
            }
    }

    if (blockIdx.x == 0 && blockIdx.y == 0 && tid == 0) {
        float s = 0.f;
        for (int hh = 0; hh < Hh; ++hh) s += 1.f / (1.f + __expf(-z[hh]));
        out[(size_t)Mm * Ed] = s * 0.01f;
    }
}

// Flash attention v25: v21 structure (best measured: 79.4us; v22/v23/v24
// alternatives all worse/neutral) + 2x TLP at constant per-wave density.
// 512 threads = 8 waves: waves 0-3 process keys [kt*128,+64), waves 4-7
// [+64,+128) -- same shared Ks dbuf (staged by all 8), same 1 barrier/kt,
// same M_rep=2 per wave. No-max softmax => partial (accO,lsum) over disjoint
// keys combine by pure addition: pair (wi,wi+4) merges via LDS at the end.
// 16 waves/CU (4/SIMD, was 2/SIMD) fills the ~60% stall fraction.
// Q arrives pre-scaled (qkv fold) => p = exp2(S) directly.
// LDS: Ks 32KB + Ps 34.8KB = 67.6KB -> 2 blocks/CU. grid (16,32), 512 thr.
__global__ __launch_bounds__(512, 4) void attn(
    const ushort_t* __restrict__ Q, const ushort_t* __restrict__ Kk,
    const ushort_t* __restrict__ Vt, const float* __restrict__ z,
    ushort_t* __restrict__ ctx)
{
    __shared__ __align__(16) char SM[67584];
    ushort_t* KsBuf = (ushort_t*)SM;                       // [2][128*64] 32KB
    // Ps: per-wave [32 q][68] at SM+32768 (8 x 4352B = 34.8KB)

    const int tid = threadIdx.x, w = tid >> 6, lane = tid & 63;
    const int wg = w >> 2;                 // key-group 0/1
    const int wi = w & 3;                  // q-slice within tile
    const int quad = lane >> 4, l15 = lane & 15;
    ushort_t* Ps_w = (ushort_t*)(SM + 32768) + w * (32 * 68);

    const int lin = blockIdx.x + 16 * blockIdx.y;   // 0..511
    const int qt = lin >> 5;                        // 0..15 (128-row q tile)
    const int bh = (lin & 7) * 4 + ((lin >> 3) & 3);// XCD-local heads
    const int h = bh & (Hh - 1), b_ = bh >> 4;
    const size_t base = (size_t)bh * Ss * Dd;

    bf16x8 aQ[2][2];
#pragma unroll
    for (int m = 0; m < 2; ++m)
#pragma unroll
        for (int c = 0; c < 2; ++c)
            aQ[m][c] = *(const bf16x8*)&Q[base
                + (size_t)(qt * 128 + wi * 32 + m * 16 + l15) * Dd + c * 32 + quad * 8];

    // K staging: wave w owns chunks {w*2, w*2+1} (rows w*16 .. w*16+15)
    const int rowc = lane >> 3;                     // 0..7
    const int gs   = ((lane & 7) ^ rowc) * 8;       // swizzled source granule
    const ushort_t* kSrcA = Kk + base + (size_t)((w * 2 + 0) * 8 + rowc) * Dd + gs;
    const ushort_t* kSrcB = Kk + base + (size_t)((w * 2 + 1) * 8 + rowc) * Dd + gs;
    // direct-V: lane row d = ni*16+l15, key offset quad*8
    const ushort_t* vBase = Vt + base + (size_t)l15 * Ss + quad * 8;

    f32x4 accO[2][4] = {};
    float lsum[2][4] = {};

    const int swq = (l15 & 7) * 8;

    // prologue: stage K-tile 0 (128 keys)
    gld16(kSrcA, (char*)KsBuf + (w * 2 + 0) * 1024);
    gld16(kSrcB, (char*)KsBuf + (w * 2 + 1) * 1024);

    for (int kt = 0; kt < Ss / 128; ++kt) {
        const int cur = kt & 1, nxt = cur ^ 1;
        __syncthreads();   // K(kt) visible; all waves done with Ks[nxt] of kt-1

        if (kt + 1 < Ss / 128) {   // prefetch K(kt+1)
            gld16(kSrcA + (size_t)(kt + 1) * 128 * Dd,
                  (char*)KsBuf + (nxt * 128 * 64 + (w * 2 + 0) * 512) * 2);
            gld16(kSrcB + (size_t)(kt + 1) * 128 * Dd,
                  (char*)KsBuf + (nxt * 128 * 64 + (w * 2 + 1) * 512) * 2);
        }

        const ushort_t* KsC = KsBuf + cur * 128 * 64;

        // S = Q K^T on this group's 64-key subtile
        f32x4 sAcc[2][4] = {};
        __builtin_amdgcn_s_setprio(1);
#pragma unroll
        for (int ni = 0; ni < 4; ++ni) {
            bf16x8 b0 = *(const bf16x8*)&KsC[(wg * 64 + ni * 16 + l15) * 64 + ((quad * 8) ^ swq)];
            bf16x8 b1 = *(const bf16x8*)&KsC[(wg * 64 + ni * 16 + l15) * 64 + (((quad + 4) * 8) ^ swq)];
#pragma unroll
            for (int m = 0; m < 2; ++m) {
                sAcc[m][ni] = __builtin_amdgcn_mfma_f32_16x16x32_bf16(aQ[m][0], b0, sAcc[m][ni], 0, 0, 0);
                sAcc[m][ni] = __builtin_amdgcn_mfma_f32_16x16x32_bf16(aQ[m][1], b1, sAcc[m][ni], 0, 0, 0);
            }
        }
        __builtin_amdgcn_s_setprio(0);

        // softmax (Q pre-scaled: p = exp2(S))
#pragma unroll
        for (int m = 0; m < 2; ++m)
#pragma unroll
            for (int ni = 0; ni < 4; ++ni)
#pragma unroll
                for (int r = 0; r < 4; ++r) {
                    float p = fast_exp2(sAcc[m][ni][r]);
                    lsum[m][r] += p;
                    Ps_w[(m * 16 + quad * 4 + r) * 68 + ni * 16 + l15] = f2bf_hi(p);
                }

        // V fragments for this group's subtile (L2-local; softmax covered issue)
        bf16x8 vf[2][4];
#pragma unroll
        for (int ni = 0; ni < 4; ++ni) {
            const ushort_t* vp = vBase + (size_t)(ni * 16) * Ss + kt * 128 + wg * 64;
            vf[0][ni] = *(const bf16x8*)(vp);
            vf[1][ni] = *(const bf16x8*)(vp + 32);
        }

        // O += P V
        __builtin_amdgcn_s_setprio(1);
#pragma unroll
        for (int c = 0; c < 2; ++c) {
            bf16x8 aP0 = *(const bf16x8*)&Ps_w[l15 * 68 + c * 32 + quad * 8];
            bf16x8 aP1 = *(const bf16x8*)&Ps_w[(16 + l15) * 68 + c * 32 + quad * 8];
#pragma unroll
            for (int ni = 0; ni < 4; ++ni) {
                accO[0][ni] = __builtin_amdgcn_mfma_f32_16x16x32_bf16(aP0, vf[c][ni], accO[0][ni], 0, 0, 0);
                accO[1][ni] = __builtin_amdgcn_mfma_f32_16x16x32_bf16(aP1, vf[c][ni], accO[1][ni], 0, 0, 0);
            }
        }
        __builtin_amdgcn_s_setprio(0);
    }

    // ---- combine wave pairs (wi, wi+4): disjoint keys => pure addition ----
    __syncthreads();                       // all main-loop LDS use done
    float* ex = (float*)SM;                // 256 slots x 41 f32 = 42KB <= 67.6KB
    const int slot = (wi * 64 + lane) * 41;
    if (wg == 1) {
#pragma unroll
        for (int m = 0; m < 2; ++m)
#pragma unroll
            for (int ni = 0; ni < 4; ++ni)
#pragma unroll
                for (int r = 0; r < 4; ++r)
                    ex[slot + m * 16 + ni * 4 + r] = accO[m][ni][r];
#pragma unroll
        for (int m = 0; m < 2; ++m)
#pragma unroll
            for (int r = 0; r < 4; ++r)
                ex[slot + 32 + m * 4 + r] = lsum[m][r];
    }
    __syncthreads();
    if (wg == 0) {
#pragma unroll
        for (int m = 0; m < 2; ++m)
#pragma unroll
            for (int ni = 0; ni < 4; ++ni)
#pragma unroll
                for (int r = 0; r < 4; ++r)
                    accO[m][ni][r] += ex[slot + m * 16 + ni * 4 + r];
#pragma unroll
        for (int m = 0; m < 2; ++m)
#pragma unroll
            for (int r = 0; r < 4; ++r) {
                lsum[m][r] += ex[slot + 32 + m * 4 + r];
                lsum[m][r] += __shfl_xor(lsum[m][r], 1);
                lsum[m][r] += __shfl_xor(lsum[m][r], 2);
                lsum[m][r] += __shfl_xor(lsum[m][r], 4);
                lsum[m][r] += __shfl_xor(lsum[m][r], 8);
            }
#pragma unroll
        for (int m = 0; m < 2; ++m)
#pragma unroll
            for (int r = 0; r < 4; ++r) {
                int srow = qt * 128 + wi * 32 + m * 16 + quad * 4 + r;
                float inv = 1.f / lsum[m][r];
#pragma unroll
                for (int ni = 0; ni < 4; ++ni) {
                    int d = ni * 16 + l15;
                    ctx[((size_t)(b_ * Ss + srow)) * Ed + h * Dd + d] = f2bf_hi(accO[m][ni][r] * inv);
                }
            }
    }
}

extern "C" void kernel_launch(void* const* d_in, const int* in_sizes, int n_in,
                              void* d_out, int out_size, void* d_ws, size_t ws_size,
                              hipStream_t stream) {
    const float* x  = (const float*)d_in[0];
    const float* Wq = (const float*)d_in[1];
    const float* bq = (const float*)d_in[2];
    const float* Wk = (const float*)d_in[3];
    const float* bk = (const float*)d_in[4];
    const float* Wv = (const float*)d_in[5];
    const float* bv = (const float*)d_in[6];
    const float* Wo = (const float*)d_in[7];
    const float* bo = (const float*)d_in[8];
    const float* z  = (const float*)d_in[9];
    float* out = (float*)d_out;

    ushort_t* xb  = (ushort_t*)d_ws;              // [M,E]     8 MB
    ushort_t* Wqb = xb  + (size_t)Mm * Ed;        // [E,E]     2 MB
    ushort_t* Wkb = Wqb + (size_t)Ed * Ed;
    ushort_t* Wvb = Wkb + (size_t)Ed * Ed;
    ushort_t* Wob = Wvb + (size_t)Ed * Ed;
    ushort_t* qw  = Wob + (size_t)Ed * Ed;        // [B,H,S,D] 8 MB
    ushort_t* kw  = qw + (size_t)Mm * Ed;         // [B,H,S,D] 8 MB
    ushort_t* vT  = kw + (size_t)Mm * Ed;         // [B,H,D,S] 8 MB
    ushort_t* cx  = vT + (size_t)Mm * Ed;         // [B,S,E]   8 MB

    cvt_all<<<dim3((NX4 + 4 * NW4) / 256), dim3(256), 0, stream>>>(
        x, Wq, Wk, Wv, Wo, xb, Wqb, Wkb, Wvb, Wob);
    qkv_gemm<<<dim3(Mm / 128, Ed / 128, 3), dim3(256), 0, stream>>>(
        xb, Wqb, bq, Wkb, bk, Wvb, bv, z, qw, kw, vT);
    attn<<<dim3(Ss / 128, 2 * Hh), dim3(512), 0, stream>>>(qw, kw, vT, z, cx);
    out_gemm<<<dim3(Mm / 128, Ed / 64), dim3(256), 0, stream>>>(cx, Wob, bo, z, out);
}